// Round 8
// baseline (221.166 us; speedup 1.0000x reference)
//
#include <hip/hip_runtime.h>
#include <hip/hip_bf16.h>

// ---------------------------------------------------------------------------
// WindGuidedCrossAttentionLayer: LN -> QKV proj -> biased attention -> out proj
// -> residual -> LN -> MLP(gelu) -> residual.  B=4, N=1024, D=768, H=12, hd=64.
// bf16 MFMA everywhere; fp32 residual path.
// ---------------------------------------------------------------------------

#define DIM 768
#define HID 3072
#define NHEAD 12
#define BATCH 4
#define SEQ 1024
#define ROWS (BATCH * SEQ)   // 4096
#define HD 64

typedef __attribute__((ext_vector_type(8))) __bf16 bf16x8;
typedef __attribute__((ext_vector_type(4))) float f32x4;
typedef __attribute__((ext_vector_type(16))) float f32x16;
typedef __attribute__((ext_vector_type(4))) unsigned int u32x4;

#define MFMA16(a, b, c) __builtin_amdgcn_mfma_f32_16x16x32_bf16((a), (b), (c), 0, 0, 0)
#define MFMA32(a, b, c) __builtin_amdgcn_mfma_f32_32x32x16_bf16((a), (b), (c), 0, 0, 0)

#define GLDS16(g, l)                                                         \
  __builtin_amdgcn_global_load_lds(                                          \
      (const __attribute__((address_space(1))) void*)(g),                    \
      (__attribute__((address_space(3))) void*)(l), 16, 0, 0)

__device__ __forceinline__ unsigned pk2(float lo, float hi) {
  unsigned a = __bfloat16_as_ushort(__float2bfloat16(lo));
  unsigned b = __bfloat16_as_ushort(__float2bfloat16(hi));
  return a | (b << 16);
}

// ---------------------------------------------------------------------------
// Fused 4x transpose+convert for the D x D weights (z picks the matrix)
// ---------------------------------------------------------------------------
__global__ __launch_bounds__(256) void wg_transpose4(const float* __restrict__ Wq,
                                                     const float* __restrict__ Wk,
                                                     const float* __restrict__ Wv,
                                                     const float* __restrict__ Wo,
                                                     __hip_bfloat16* __restrict__ WqT,
                                                     __hip_bfloat16* __restrict__ WkT,
                                                     __hip_bfloat16* __restrict__ WvT,
                                                     __hip_bfloat16* __restrict__ WoT) {
  __shared__ float tile[32][33];
  const int z = blockIdx.z;
  const float* W = (z == 0) ? Wq : (z == 1) ? Wk : (z == 2) ? Wv : Wo;
  __hip_bfloat16* WT = (z == 0) ? WqT : (z == 1) ? WkT : (z == 2) ? WvT : WoT;
  const int tx = threadIdx.x & 31, ty = threadIdx.x >> 5;  // ty 0..7
  const int n0 = blockIdx.x * 32, k0 = blockIdx.y * 32;
#pragma unroll
  for (int i = 0; i < 4; i++)
    tile[ty + i * 8][tx] = W[(size_t)(k0 + ty + i * 8) * DIM + n0 + tx];
  __syncthreads();
#pragma unroll
  for (int i = 0; i < 4; i++)
    WT[(size_t)(n0 + ty + i * 8) * DIM + k0 + tx] = __float2bfloat16(tile[tx][ty + i * 8]);
}

// general transpose for W1/W2
__global__ __launch_bounds__(256) void wg_transpose(const float* __restrict__ W,
                                                    __hip_bfloat16* __restrict__ WT,
                                                    int K, int N) {
  __shared__ float tile[32][33];
  const int tx = threadIdx.x & 31, ty = threadIdx.x >> 5;
  const int n0 = blockIdx.x * 32, k0 = blockIdx.y * 32;
#pragma unroll
  for (int i = 0; i < 4; i++)
    tile[ty + i * 8][tx] = W[(size_t)(k0 + ty + i * 8) * N + n0 + tx];
  __syncthreads();
#pragma unroll
  for (int i = 0; i < 4; i++)
    WT[(size_t)(n0 + ty + i * 8) * K + k0 + tx] = __float2bfloat16(tile[tx][ty + i * 8]);
}

// concat 3 bias vectors into bcat[2304]
__global__ void wg_bcat(const float* __restrict__ bq, const float* __restrict__ bk,
                        const float* __restrict__ bv, float* __restrict__ bc) {
  int i = blockIdx.x * 256 + threadIdx.x;
  if (i < 768) bc[i] = bq[i];
  else if (i < 1536) bc[i] = bk[i - 768];
  else if (i < 2304) bc[i] = bv[i - 1536];
}

// ---------------------------------------------------------------------------
// LayerNorm over 768, fp32 in -> bf16 out.  DUAL=1: two inputs, contiguous out.
// ---------------------------------------------------------------------------
template <int DUAL>
__global__ __launch_bounds__(256) void wg_ln(const float* __restrict__ inA,
                                             const float* __restrict__ wA,
                                             const float* __restrict__ bA,
                                             const float* __restrict__ inB,
                                             const float* __restrict__ wB,
                                             const float* __restrict__ bB,
                                             __hip_bfloat16* __restrict__ outbuf) {
  int row = blockIdx.x;
  int t = threadIdx.x;
  const float* in = inA;
  const float* w = wA;
  const float* b = bA;
  int lrow = row;
  if (DUAL && row >= ROWS) {
    in = inB; w = wB; b = bB; lrow = row - ROWS;
  }
  const float* p = in + (size_t)lrow * DIM;
  float v0 = p[t], v1 = p[t + 256], v2 = p[t + 512];
  float s = v0 + v1 + v2;
  float q = v0 * v0 + v1 * v1 + v2 * v2;
#pragma unroll
  for (int d = 1; d < 64; d <<= 1) {
    s += __shfl_xor(s, d);
    q += __shfl_xor(q, d);
  }
  __shared__ float ss[4], sq[4];
  if ((t & 63) == 0) {
    ss[t >> 6] = s;
    sq[t >> 6] = q;
  }
  __syncthreads();
  s = ss[0] + ss[1] + ss[2] + ss[3];
  q = sq[0] + sq[1] + sq[2] + sq[3];
  float mu = s * (1.0f / DIM);
  float var = q * (1.0f / DIM) - mu * mu;
  float rs = rsqrtf(var + 1e-5f);
  __hip_bfloat16* o = outbuf + (size_t)row * DIM;
  o[t] = __float2bfloat16((v0 - mu) * rs * w[t] + b[t]);
  o[t + 256] = __float2bfloat16((v1 - mu) * rs * w[t + 256] + b[t + 256]);
  o[t + 512] = __float2bfloat16((v2 - mu) * rs * w[t + 512] + b[t + 512]);
}

// ---------------------------------------------------------------------------
// GEMM: 128x128 tile, BK=32, 512 threads, triple-buffered counted-vmcnt
// pipeline (proven round 7).  MODE 3: resid-add f32; 4: gelu bf16; 6: fused
// QKV; 7: split-K partial.
// ---------------------------------------------------------------------------
template <int MODE>
__global__ __launch_bounds__(512) void wg_gemm(const __hip_bfloat16* __restrict__ A,
                                               const __hip_bfloat16* __restrict__ BT,
                                               const float* __restrict__ bias,
                                               void* __restrict__ Cout,
                                               const float* __restrict__ resid,
                                               float* __restrict__ aux,
                                               int N, int Kloop, int Kstride, float p0) {
  __shared__ __hip_bfloat16 As[3][128 * 32];
  __shared__ __hip_bfloat16 Bs[3][128 * 32];
  const int t = threadIdx.x;
  const int lane = t & 63;
  const int wave = t >> 6;           // 0..7
  const int wr = wave >> 1, wc = wave & 1;
  const int lhi = lane >> 4, llo = lane & 15;
  const int nbn = N >> 7;
  const int bm = blockIdx.x / nbn, bn = blockIdx.x % nbn;
  const int koff = (MODE == 7) ? blockIdx.y * Kloop : 0;

  const __hip_bfloat16* Ause = A;
  if (MODE == 6 && bn >= 6) Ause = A + (size_t)ROWS * DIM;  // kvln

  const int srow = t >> 2;
  const int sg = ((t & 3) ^ ((srow >> 1) & 3)) * 8;
  const __hip_bfloat16* Ag = Ause + (size_t)(bm * 128 + srow) * Kstride + koff + sg;
  const __hip_bfloat16* Bg = BT + (size_t)(bn * 128 + srow) * Kstride + koff + sg;

  f32x4 zero = {0.f, 0.f, 0.f, 0.f};
  f32x4 acc[2][4];
#pragma unroll
  for (int i = 0; i < 2; i++)
#pragma unroll
    for (int j = 0; j < 4; j++) acc[i][j] = zero;

  const int nk = Kloop >> 5;   // K-steps of 32

  GLDS16(Ag, &As[0][t * 8]);
  GLDS16(Bg, &Bs[0][t * 8]);
  GLDS16(Ag + 32, &As[1][t * 8]);
  GLDS16(Bg + 32, &Bs[1][t * 8]);

  int buf = 0;
  for (int kt = 0; kt < nk; kt++) {
    if (kt < nk - 1) {
      asm volatile("s_waitcnt vmcnt(2)" ::: "memory");
    } else {
      asm volatile("s_waitcnt vmcnt(0)" ::: "memory");
    }
    __builtin_amdgcn_s_barrier();
    asm volatile("" ::: "memory");
    if (kt + 2 < nk) {
      int nbuf = buf + 2;
      if (nbuf >= 3) nbuf -= 3;
      GLDS16(Ag + (kt + 2) * 32, &As[nbuf][t * 8]);
      GLDS16(Bg + (kt + 2) * 32, &Bs[nbuf][t * 8]);
    }
    bf16x8 af[2], bfr[4];
#pragma unroll
    for (int i = 0; i < 2; i++) {
      const int row = wr * 32 + i * 16 + llo;
      af[i] = *reinterpret_cast<const bf16x8*>(
          &As[buf][row * 32 + ((lhi ^ ((row >> 1) & 3)) << 3)]);
    }
#pragma unroll
    for (int j = 0; j < 4; j++) {
      const int row = wc * 64 + j * 16 + llo;
      bfr[j] = *reinterpret_cast<const bf16x8*>(
          &Bs[buf][row * 32 + ((lhi ^ ((row >> 1) & 3)) << 3)]);
    }
    __builtin_amdgcn_s_setprio(1);
#pragma unroll
    for (int i = 0; i < 2; i++)
#pragma unroll
      for (int j = 0; j < 4; j++) acc[i][j] = MFMA16(af[i], bfr[j], acc[i][j]);
    __builtin_amdgcn_s_setprio(0);
    buf++;
    if (buf == 3) buf = 0;
  }

#pragma unroll
  for (int i = 0; i < 2; i++) {
    int gr = bm * 128 + wr * 32 + i * 16 + lhi * 4;
#pragma unroll
    for (int j = 0; j < 4; j++) {
      int gc = bn * 128 + wc * 64 + j * 16 + llo;
      float bv_ = (MODE == 7) ? 0.f : bias[gc];
#pragma unroll
      for (int r = 0; r < 4; r++) {
        float v = acc[i][j][r] + bv_;
        int row = gr + r;
        size_t idx = (size_t)row * N + gc;
        if (MODE == 3) {
          aux[idx] = resid[idx] + v;
        } else if (MODE == 4) {
          float x3 = v * v * v;
          float z = -2.302208f * v - 0.102943f * x3;
          float g = v / (1.0f + exp2f(z));
          ((__hip_bfloat16*)Cout)[idx] = __float2bfloat16(g);
        } else if (MODE == 7) {
          aux[(size_t)blockIdx.y * ROWS * N + idx] = v;
        } else if (MODE == 6) {
          int sec = gc / 768;
          int n2 = gc - sec * 768;
          __hip_bfloat16* base = (__hip_bfloat16*)Cout;
          if (sec == 0) {
            base[(size_t)row * DIM + n2] = __float2bfloat16(v * p0);
          } else if (sec == 1) {
            base[(size_t)ROWS * DIM + (size_t)row * DIM + n2] = __float2bfloat16(v);
          } else {
            int b_ = row >> 10, n_ = row & 1023;
            int h_ = n2 >> 6, d_ = n2 & 63;
            base[(size_t)2 * ROWS * DIM +
                 (((size_t)(b_ * NHEAD + h_) * HD + d_) << 10) + n_] = __float2bfloat16(v);
          }
        }
      }
    }
  }
}

// ---------------------------------------------------------------------------
// Split-K reduce
// ---------------------------------------------------------------------------
template <int NP>
__global__ __launch_bounds__(256) void wg_red(const float* __restrict__ partial,
                                              const float* __restrict__ resid,
                                              const float* __restrict__ bias,
                                              float* __restrict__ out) {
  const int i = blockIdx.x * 256 + threadIdx.x;
  const int NF4 = ROWS * DIM / 4;
  if (i >= NF4) return;
  const f32x4* P = (const f32x4*)partial;
  f32x4 p = P[i];
#pragma unroll
  for (int c = 1; c < NP; c++) p += P[i + c * NF4];
  f32x4 r = ((const f32x4*)resid)[i];
  f32x4 bv = ((const f32x4*)bias)[i % (DIM / 4)];
  ((f32x4*)out)[i] = r + p + bv;
}

// ---------------------------------------------------------------------------
// Flash attention v6: 32x32x16 MFMAs, 32 q-rows/wave, 2 waves/block (64 q),
// grid 768 (3 blocks/CU balanced), XCD-chunked.  Swapped QK^T -> S^T spread
// over lane&31(q) x lane>>5(kv-half): softmax = in-lane 32-reg tree + ONE
// cross-32 exchange.  P^T built with 8 cross-32 exchanges (vs 16 bpermutes).
// PV = mfma(V^T, P^T): corr and 1/l fully lane-local.  LDS-pipe ops per
// 32q-tile: 72 -> 26.
// ---------------------------------------------------------------------------
#define PACKG(S, G2, OUT)                                                     \
  {                                                                           \
    unsigned pA0 = pk2((S)[8 * (G2) + 0], (S)[8 * (G2) + 1]);                 \
    unsigned pA1 = pk2((S)[8 * (G2) + 2], (S)[8 * (G2) + 3]);                 \
    unsigned pB0 = pk2((S)[8 * (G2) + 4], (S)[8 * (G2) + 5]);                 \
    unsigned pB1 = pk2((S)[8 * (G2) + 6], (S)[8 * (G2) + 7]);                 \
    unsigned u0 = l5 ? pB0 : pA0, v0 = l5 ? pA0 : pB0;                        \
    unsigned u1 = l5 ? pB1 : pA1, v1 = l5 ? pA1 : pB1;                        \
    unsigned w0 = (unsigned)__shfl_xor((int)v0, 32);                          \
    unsigned w1 = (unsigned)__shfl_xor((int)v1, 32);                          \
    u32x4 tb_;                                                                \
    tb_[0] = l5 ? w0 : u0;                                                    \
    tb_[1] = l5 ? w1 : u1;                                                    \
    tb_[2] = l5 ? u0 : w0;                                                    \
    tb_[3] = l5 ? u1 : w1;                                                    \
    OUT = __builtin_bit_cast(bf16x8, tb_);                                    \
  }

__global__ __launch_bounds__(128) void wg_attn6(const __hip_bfloat16* __restrict__ Q,
                                                const __hip_bfloat16* __restrict__ Kb,
                                                const __hip_bfloat16* __restrict__ Vt,
                                                const float* __restrict__ wb,
                                                const float* __restrict__ beta,
                                                __hip_bfloat16* __restrict__ O) {
  __shared__ __align__(16) __hip_bfloat16 Ks[2][4096];
  __shared__ __align__(16) __hip_bfloat16 Vs[2][4096];
  const int t = threadIdx.x;           // 0..127
  const int lane = t & 63;
  const int w = t >> 6;                // wave 0..1
  const int l5 = lane >> 5;
  const int l31 = lane & 31;

  // XCD-chunked decode: 768 = 8 chunks x 96; h fastest within chunk.
  const int bid = blockIdx.x;
  const int wid = (bid & 7) * 96 + (bid >> 3);
  const int h = wid % NHEAD;
  const int g = wid / NHEAD;       // 0..63
  const int qt = g & 15;
  const int b = g >> 4;
  const float betah = beta[h] * 1.44269504089f;

  const int qrow0 = b * SEQ + qt * 64 + w * 32;   // wave's 32-q base
  const __hip_bfloat16* Qp = Q + (size_t)(qrow0 + l31) * DIM + h * HD + l5 * 8;
  bf16x8 qf[4];
#pragma unroll
  for (int hc = 0; hc < 4; hc++)
    qf[hc] = *reinterpret_cast<const bf16x8*>(&Qp[hc * 16]);

  const __hip_bfloat16* Kg = Kb + (size_t)b * SEQ * DIM + h * HD;
  const __hip_bfloat16* Vg = Vt + (size_t)(b * NHEAD + h) * HD * SEQ;
  const float* wrow = wb + (size_t)(qrow0 + l31) * SEQ + l5 * 4;

  // staging: 512 slots/buffer, thread covers t + 128*i
  int sr[4], sc[4];
#pragma unroll
  for (int i = 0; i < 4; i++) {
    int s = t + 128 * i;
    sr[i] = s >> 3;
    sc[i] = ((s & 7) ^ (sr[i] & 7)) * 8;
  }
  auto stage = [&](int buf, int kb) {
#pragma unroll
    for (int i = 0; i < 4; i++) {
      GLDS16(Kg + (size_t)(kb + sr[i]) * DIM + sc[i], &Ks[buf][(t + 128 * i) * 8]);
      GLDS16(Vg + (size_t)sr[i] * SEQ + kb + sc[i], &Vs[buf][(t + 128 * i) * 8]);
    }
  };

  f32x16 oc0, oc1;
#pragma unroll
  for (int i = 0; i < 16; i++) {
    oc0[i] = 0.f;
    oc1[i] = 0.f;
  }
  float m_ = -1e30f, l_ = 0.f;   // per-lane: q = qrow0 + l31 (both l5 halves agree)

  f32x4 wv[8];
#pragma unroll
  for (int i = 0; i < 8; i++) wv[i] = *reinterpret_cast<const f32x4*>(&wrow[i * 8]);

  stage(0, 0);
  __syncthreads();
  int cur = 0;

  for (int kt = 0; kt < 16; kt++) {
    const int kb = kt * 64;
    if (kt < 15) stage(cur ^ 1, kb + 64);

    // ---- QK^T (swapped): S^T[kv][q], kv blocks 0-31 / 32-63 ----
    f32x16 s0, s1;
#pragma unroll
    for (int i = 0; i < 16; i++) {
      s0[i] = 0.f;
      s1[i] = 0.f;
    }
    __builtin_amdgcn_s_setprio(1);
#pragma unroll
    for (int hc = 0; hc < 4; hc++) {
      const int row = l31;
      bf16x8 kf = *reinterpret_cast<const bf16x8*>(
          &Ks[cur][row * 64 + (((hc * 2 + l5) ^ (row & 7)) << 3)]);
      s0 = MFMA32(kf, qf[hc], s0);
    }
#pragma unroll
    for (int hc = 0; hc < 4; hc++) {
      const int row = 32 + l31;
      bf16x8 kf = *reinterpret_cast<const bf16x8*>(
          &Ks[cur][row * 64 + (((hc * 2 + l5) ^ (row & 7)) << 3)]);
      s1 = MFMA32(kf, qf[hc], s1);
    }
    __builtin_amdgcn_s_setprio(0);

    // ---- bias: s[blk][4rq+rb] += betah * wv[rq+4blk][rb] ----
#pragma unroll
    for (int rq = 0; rq < 4; rq++)
#pragma unroll
      for (int rb = 0; rb < 4; rb++) {
        s0[4 * rq + rb] += betah * wv[rq][rb];
        s1[4 * rq + rb] += betah * wv[rq + 4][rb];
      }
    // prefetch next tile's wind bias (reuses wv regs)
    if (kt < 15) {
#pragma unroll
      for (int i = 0; i < 8; i++)
        wv[i] = *reinterpret_cast<const f32x4*>(&wrow[kb + 64 + i * 8]);
    }

    // ---- row max: in-lane tree over 32 regs + one cross-32 ----
    float mx;
    {
      f32x4 m4;
#pragma unroll
      for (int r = 0; r < 4; r++) {
        float a_ = fmaxf(fmaxf(s0[r], s0[4 + r]), fmaxf(s0[8 + r], s0[12 + r]));
        float b_ = fmaxf(fmaxf(s1[r], s1[4 + r]), fmaxf(s1[8 + r], s1[12 + r]));
        m4[r] = fmaxf(a_, b_);
      }
      mx = fmaxf(fmaxf(m4[0], m4[1]), fmaxf(m4[2], m4[3]));
      mx = fmaxf(mx, __shfl_xor(mx, 32));
    }

    const bool grow = __any(mx > m_);
    float corr = 1.f;
    if (grow) {
      float mn = fmaxf(m_, mx);
      corr = exp2f(m_ - mn);
      m_ = mn;
    }

    // ---- exp2 + row sum ----
    float rs = 0.f;
#pragma unroll
    for (int i = 0; i < 16; i++) {
      s0[i] = exp2f(s0[i] - m_);
      s1[i] = exp2f(s1[i] - m_);
      rs += s0[i] + s1[i];
    }
    rs += __shfl_xor(rs, 32);
    l_ = l_ * corr + rs;

    if (grow) {
#pragma unroll
      for (int i = 0; i < 16; i++) {
        oc0[i] *= corr;
        oc1[i] *= corr;
      }
    }

    // ---- build P^T B-frags (4 kv-groups of 16) ----
    bf16x8 pb0, pb1, pb2, pb3;
    PACKG(s0, 0, pb0);
    PACKG(s0, 1, pb1);
    PACKG(s1, 0, pb2);
    PACKG(s1, 1, pb3);

    // ---- PV: O^T[d][q] += V^T[d][kv] * P^T[kv][q] ----
    __builtin_amdgcn_s_setprio(1);
#pragma unroll
    for (int gi = 0; gi < 4; gi++) {
      const bf16x8 pb = (gi == 0) ? pb0 : (gi == 1) ? pb1 : (gi == 2) ? pb2 : pb3;
      {
        const int row = l31;
        bf16x8 vf = *reinterpret_cast<const bf16x8*>(
            &Vs[cur][row * 64 + (((gi * 2 + l5) ^ (row & 7)) << 3)]);
        oc0 = MFMA32(vf, pb, oc0);
      }
      {
        const int row = 32 + l31;
        bf16x8 vf = *reinterpret_cast<const bf16x8*>(
            &Vs[cur][row * 64 + (((gi * 2 + l5) ^ (row & 7)) << 3)]);
        oc1 = MFMA32(vf, pb, oc1);
      }
    }
    __builtin_amdgcn_s_setprio(0);

    __syncthreads();
    cur ^= 1;
  }

  // ---- epilogue: normalize, transpose via per-wave LDS region, store ----
  const float inv = 1.0f / l_;
  unsigned* tbuf = (unsigned*)((w == 0) ? (void*)&Ks[0][0] : (void*)&Vs[0][0]);
  // region layout: [q=32][36 u32] (stride 36 keeps 16B alignment for b128 reads)
#pragma unroll
  for (int rq = 0; rq < 4; rq++) {
    // d0 = 8rq + 4l5 (+32 for oc1); u32 col = d0/2 = 4rq + 2l5 (+16)
    unsigned a0 = pk2(oc0[4 * rq + 0] * inv, oc0[4 * rq + 1] * inv);
    unsigned a1 = pk2(oc0[4 * rq + 2] * inv, oc0[4 * rq + 3] * inv);
    unsigned b0 = pk2(oc1[4 * rq + 0] * inv, oc1[4 * rq + 1] * inv);
    unsigned b1 = pk2(oc1[4 * rq + 2] * inv, oc1[4 * rq + 3] * inv);
    tbuf[l31 * 36 + 4 * rq + 2 * l5 + 0] = a0;
    tbuf[l31 * 36 + 4 * rq + 2 * l5 + 1] = a1;
    tbuf[l31 * 36 + 4 * rq + 2 * l5 + 16] = b0;
    tbuf[l31 * 36 + 4 * rq + 2 * l5 + 17] = b1;
  }
  asm volatile("s_waitcnt lgkmcnt(0)" ::: "memory");
  // readback: lane -> q = lane>>1, half = lane&1; 16 u32 per lane
  unsigned* outp = (unsigned*)O;
  const int q_ = lane >> 1, hf = lane & 1;
#pragma unroll
  for (int i = 0; i < 4; i++) {
    u32x4 vv = *reinterpret_cast<const u32x4*>(&tbuf[q_ * 36 + hf * 16 + i * 4]);
    *reinterpret_cast<u32x4*>(
        &outp[(size_t)(qrow0 + q_) * 384 + h * 32 + hf * 16 + i * 4]) = vv;
  }
}

// ---------------------------------------------------------------------------
// Launch
// ---------------------------------------------------------------------------
extern "C" void kernel_launch(void* const* d_in, const int* in_sizes, int n_in,
                              void* d_out, int out_size, void* d_ws, size_t ws_size,
                              hipStream_t stream) {
  const float* query = (const float*)d_in[0];
  const float* context = (const float*)d_in[1];
  const float* wind = (const float*)d_in[2];
  const float* ln_q_w = (const float*)d_in[3];
  const float* ln_q_b = (const float*)d_in[4];
  const float* ln_kv_w = (const float*)d_in[5];
  const float* ln_kv_b = (const float*)d_in[6];
  const float* Wq = (const float*)d_in[7];
  const float* bq = (const float*)d_in[8];
  const float* Wk = (const float*)d_in[9];
  const float* bk = (const float*)d_in[10];
  const float* Wv = (const float*)d_in[11];
  const float* bv = (const float*)d_in[12];
  const float* Wo = (const float*)d_in[13];
  const float* bo = (const float*)d_in[14];
  const float* beta = (const float*)d_in[15];
  const float* ln_f_w = (const float*)d_in[16];
  const float* ln_f_b = (const float*)d_in[17];
  const float* W1 = (const float*)d_in[18];
  const float* b1 = (const float*)d_in[19];
  const float* W2 = (const float*)d_in[20];
  const float* b2 = (const float*)d_in[21];
  float* out = (float*)d_out;

  char* ws = (char*)d_ws;
  size_t off = 0;
  auto take = [&](size_t bytes) -> char* {
    char* p = ws + off;
    off += (bytes + 255) & ~(size_t)255;
    return p;
  };
  const size_t actB = (size_t)ROWS * DIM * 2;
  __hip_bfloat16* qln = (__hip_bfloat16*)take(actB);
  __hip_bfloat16* kvln = (__hip_bfloat16*)take(actB);
  __hip_bfloat16* qb = (__hip_bfloat16*)take(actB);
  __hip_bfloat16* kbuf = (__hip_bfloat16*)take(actB);
  __hip_bfloat16* vt = (__hip_bfloat16*)take(actB);
  __hip_bfloat16* aout = (__hip_bfloat16*)take(actB);
  __hip_bfloat16* hbuf = (__hip_bfloat16*)take(actB);
  float* xbuf = (float*)take((size_t)ROWS * DIM * 4);
  __hip_bfloat16* hid = (__hip_bfloat16*)take((size_t)ROWS * HID * 2);
  __hip_bfloat16* WqT = (__hip_bfloat16*)take((size_t)DIM * DIM * 2);
  __hip_bfloat16* WkT = (__hip_bfloat16*)take((size_t)DIM * DIM * 2);
  __hip_bfloat16* WvT = (__hip_bfloat16*)take((size_t)DIM * DIM * 2);
  __hip_bfloat16* WoT = (__hip_bfloat16*)take((size_t)DIM * DIM * 2);
  __hip_bfloat16* W1T = (__hip_bfloat16*)take((size_t)DIM * HID * 2);
  __hip_bfloat16* W2T = (__hip_bfloat16*)take((size_t)HID * DIM * 2);
  float* bcat = (float*)take(2304 * 4);
  float* kpart = (float*)take((size_t)4 * ROWS * DIM * 4);

  wg_transpose4<<<dim3(24, 24, 4), 256, 0, stream>>>(Wq, Wk, Wv, Wo, WqT, WkT, WvT, WoT);
  wg_transpose<<<dim3(96, 24), 256, 0, stream>>>(W1, W1T, DIM, HID);
  wg_transpose<<<dim3(24, 96), 256, 0, stream>>>(W2, W2T, HID, DIM);
  wg_bcat<<<9, 256, 0, stream>>>(bq, bk, bv, bcat);

  wg_ln<1><<<2 * ROWS, 256, 0, stream>>>(query, ln_q_w, ln_q_b,
                                         context, ln_kv_w, ln_kv_b, qln);

  const float scale = 0.125f * 1.44269504089f;  // hd^-0.5 * log2(e)
  wg_gemm<6><<<32 * 18, 512, 0, stream>>>(qln, WqT, bcat, qb, nullptr, nullptr,
                                          2304, DIM, DIM, scale);

  wg_attn6<<<768, 128, 0, stream>>>(qb, kbuf, vt, wind, beta, aout);

  const int g768 = (ROWS / 128) * (DIM / 128);   // 192
  const int g3072 = (ROWS / 128) * (HID / 128);  // 768
  wg_gemm<3><<<g768, 512, 0, stream>>>(aout, WoT, bo, nullptr, query, xbuf, DIM, DIM, DIM, 0.f);
  wg_ln<0><<<ROWS, 256, 0, stream>>>(xbuf, ln_f_w, ln_f_b, nullptr, nullptr, nullptr, hbuf);
  wg_gemm<4><<<g3072, 512, 0, stream>>>(hbuf, W1T, b1, hid, nullptr, nullptr, HID, DIM, DIM, 0.f);
  wg_gemm<7><<<dim3(g768, 4), 512, 0, stream>>>(hid, W2T, nullptr, nullptr, nullptr, kpart,
                                                DIM, HID / 4, HID, 0.f);
  wg_red<4><<<(ROWS * DIM / 4 + 255) / 256, 256, 0, stream>>>(kpart, xbuf, b2, out);
}